// Round 10
// baseline (1658.240 us; speedup 1.0000x reference)
//
#include <hip/hip_runtime.h>
#include <hip/hip_bf16.h>

typedef __hip_bfloat16 bf16;

#define NN  100000   // nodes
#define EE  800000   // edges
#define FN_ 128      // node feature dim
#define FE_ 16       // edge feature dim
#define HN  200      // hidden dim
#define TT  8        // towers
#define DT_ 25       // per-tower dim
#define GG  64       // graphs
#define STEPS_ 3

#define NPB 64       // dst nodes per msg block (4 waves x GW)
#define GW  16       // dst nodes per wave (wave-autonomous)
#define GSTR 212     // gate_s row stride in shorts
#define NRB 128      // nodes per scatter block
#define NXCD 8       // XCDs on MI355X

// MFMA geometry
#define MB3  64      // nodes per gru block (4 row-tiles of 16) -- round-6 proven config
#define XSTR 456     // gru LDS X row stride in shorts
#define CTN  13      // col tiles (13*16 = 208 >= 200)
#define KTN  14      // gru k tiles (14*32 = 448 = 224(m) + 224(h))
#define WBSZ (3 * KTN * CTN * 512)   // gru packed weight shorts

// pack_all region sizes
#define PA_A (WBSZ + 3 * 208)
#define PA_B (7 * CTN * 512 + 208)
#define PA_C (7 * CTN * 512 + 208)
#define PA_D (4 * CTN * 512 + 208)
#define PA_E (FE_ * HN + HN)
#define PA_F (CTN * 512 + 208)
#define PA_TOT (PA_A + PA_B + PA_C + PA_D + PA_E + PA_F)

typedef __attribute__((ext_vector_type(8))) short short8v;
typedef __attribute__((ext_vector_type(4))) float f32x4;
typedef __attribute__((ext_vector_type(2))) unsigned int uint2v;
#define MFMA16(a, b, c) __builtin_amdgcn_mfma_f32_16x16x32_bf16(a, b, c, 0, 0, 0)

__device__ __forceinline__ float b2f(bf16 v) { return __bfloat162float(v); }
__device__ __forceinline__ float us2f(unsigned short u) { return __uint_as_float((unsigned)u << 16); }
__device__ __forceinline__ float lo2f(unsigned u) { return __uint_as_float(u << 16); }
__device__ __forceinline__ float hi2f(unsigned u) { return __uint_as_float(u & 0xffff0000u); }
__device__ __forceinline__ unsigned short f2us(float x) { bf16 t = __float2bfloat16(x); return *(unsigned short*)&t; }
__device__ __forceinline__ float sigmf(float x) { return 1.0f / (1.0f + __expf(-x)); }

template <typename T> struct LDR;
template <> struct LDR<bf16> {
    static __device__ __forceinline__ float get(const void* p, size_t i) {
        return __bfloat162float(((const bf16*)p)[i]);
    }
};
template <> struct LDR<float> {
    static __device__ __forceinline__ float get(const void* p, size_t i) {
        return ((const float*)p)[i];
    }
};
__device__ __forceinline__ float ldsel(const void* p, size_t i, int f) {
    return f ? LDR<float>::get(p, i) : LDR<bf16>::get(p, i);
}

__device__ __forceinline__ unsigned ordkey(float x) {
    unsigned b = __float_as_uint(x);
    return b ^ (unsigned)(((int)b >> 31) | (int)0x80000000);
}
__device__ __forceinline__ float ordinv(unsigned u) {
    unsigned b = (u & 0x80000000u) ? (u ^ 0x80000000u) : ~u;
    return __uint_as_float(b);
}

// ---------------- dtype probe ----------------
__global__ __launch_bounds__(256) void probe_k(const void* nf, const void* Win, int* flag) {
    __shared__ int cnt;
    if (threadIdx.x == 0) cnt = 0;
    __syncthreads();
    const unsigned short* a = (const unsigned short*)nf;
    const unsigned short* b = (const unsigned short*)Win;
    int c = 0;
    for (int i = threadIdx.x; i < 2048; i += 256) {
        float x = us2f(a[i]);
        float y = us2f(b[i]);
        if (!(fabsf(x) < 1e3f)) c++;
        if (!(fabsf(y) < 1e3f)) c++;
    }
    atomicAdd(&cnt, c);
    __syncthreads();
    if (threadIdx.x == 0) flag[0] = (cnt >= 8) ? 1 : 0;
}

// ---------------- zero fill ----------------
__global__ __launch_bounds__(256) void zero_k(float4* __restrict__ p, int n4) {
    int i = blockIdx.x * 256 + threadIdx.x;
    if (i < n4) p[i] = float4{0.f, 0.f, 0.f, 0.f};
}

// ---------------- ALL weight packs in one kernel ----------------
__global__ __launch_bounds__(256) void pack_all_k(
    const int* flag,
    const void* Wz, const void* Uz, const void* bz,
    const void* Wr, const void* Ur, const void* br,
    const void* Wh, const void* Uh, const void* bh,
    const void* Wt, const void* Wmix, const void* bmix,
    const void* Wfeat, const void* bfeat, const void* Wscore, const void* bscore,
    const void* Win, const void* bin,
    const void* Wedge, const void* bedge,
    short* __restrict__ WB, float* __restrict__ bpack,
    short* __restrict__ WBmix, float* __restrict__ bpmix,
    short* __restrict__ WBfs, float* __restrict__ bpfs,
    short* __restrict__ WBin, float* __restrict__ bpin,
    float* __restrict__ Wef, float* __restrict__ bef,
    short* __restrict__ WBedge, float* __restrict__ bpedge)
{
    int i = blockIdx.x * 256 + threadIdx.x;
    const int f = *flag;

    if (i < PA_A) {                       // ---- region A: GRU gates [W;U] K=448
        if (i < WBSZ) {
            int j8 = i & 7;
            int e = i >> 3;
            int lane = e & 63; e >>= 6;
            int ct = e % 13; e /= 13;
            int kt = e % 14;
            int g = e / 14;
            int kl = kt * 32 + (lane >> 4) * 8 + j8;
            int col = ct * 16 + (lane & 15);
            int ksrc = (kl < 224) ? kl : kl - 224;
            const void* W = (kl < 224) ? (g == 0 ? Wz : g == 1 ? Wr : Wh)
                                       : (g == 0 ? Uz : g == 1 ? Ur : Uh);
            float v = 0.f;
            if (ksrc < HN && col < HN) v = ldsel(W, (size_t)ksrc * HN + col, f);
            WB[i] = (short)f2us(v);
        } else {
            int t = i - WBSZ;
            int g = t / 208, col = t % 208;
            const void* B = g == 0 ? bz : g == 1 ? br : bh;
            bpack[t] = (col < HN) ? ldsel(B, col, f) : 0.f;
        }
        return;
    }
    i -= PA_A;
    if (i < PA_B) {                       // ---- region B: W_eff = blockdiag(W_tower)@W_mix
        const int tot = 7 * CTN * 512;
        if (i < tot) {
            int j8 = i & 7;
            int e = i >> 3;
            int lane = e & 63; e >>= 6;
            int ct = e % CTN;
            int kt = e / CTN;
            int kl = kt * 32 + (lane >> 4) * 8 + j8;
            int col = ct * 16 + (lane & 15);
            float v = 0.f;
            if (kl < HN && col < HN) {
                int t = kl / DT_, d = kl - t * DT_;
                for (int ee = 0; ee < DT_; ee++) {
                    float wt = ldsel(Wt, (size_t)(t * DT_ + d) * DT_ + ee, f);
                    float wm = ldsel(Wmix, (size_t)(t * DT_ + ee) * HN + col, f);
                    v = fmaf(wt, wm, v);
                }
            }
            WBmix[i] = (short)f2us(v);
        } else {
            int t = i - tot;
            bpmix[t] = (t < HN) ? ldsel(bmix, t, f) : 0.f;
        }
        return;
    }
    i -= PA_B;
    if (i < PA_C) {                       // ---- region C: W_feat with W_score as col 200
        const int tot = 7 * CTN * 512;
        if (i < tot) {
            int j8 = i & 7;
            int e = i >> 3;
            int lane = e & 63; e >>= 6;
            int ct = e % CTN;
            int kt = e / CTN;
            int kl = kt * 32 + (lane >> 4) * 8 + j8;
            int col = ct * 16 + (lane & 15);
            float v = 0.f;
            if (kl < HN) {
                if (col < HN) v = ldsel(Wfeat, (size_t)kl * HN + col, f);
                else if (col == HN) v = ldsel(Wscore, kl, f);
            }
            WBfs[i] = (short)f2us(v);
        } else {
            int t = i - tot;
            float v = 0.f;
            if (t < HN) v = ldsel(bfeat, t, f);
            else if (t == HN) v = ldsel(bscore, 0, f);
            bpfs[t] = v;
        }
        return;
    }
    i -= PA_C;
    if (i < PA_D) {                       // ---- region D: W_in (K=128)
        const int tot = 4 * CTN * 512;
        if (i < tot) {
            int j8 = i & 7;
            int e = i >> 3;
            int lane = e & 63; e >>= 6;
            int ct = e % CTN;
            int kt = e / CTN;
            int kl = kt * 32 + (lane >> 4) * 8 + j8;
            int col = ct * 16 + (lane & 15);
            float v = 0.f;
            if (kl < FN_ && col < HN) v = ldsel(Win, (size_t)kl * HN + col, f);
            WBin[i] = (short)f2us(v);
        } else {
            int t = i - tot;
            bpin[t] = (t < HN) ? ldsel(bin, t, f) : 0.f;
        }
        return;
    }
    i -= PA_D;
    if (i < PA_E) {                       // ---- region E: W_edge as f32 + b_edge (legacy)
        if (i < FE_ * HN) Wef[i] = ldsel(Wedge, i, f);
        else bef[i - FE_ * HN] = ldsel(bedge, i - FE_ * HN, f);
        return;
    }
    i -= PA_E;
    if (i < PA_F) {                       // ---- region F: W_edge MFMA pack (KT=1, K=16 padded to 32)
        const int tot = CTN * 512;
        if (i < tot) {
            int j8 = i & 7;
            int e = i >> 3;
            int lane = e & 63; e >>= 6;
            int ct = e;                    // KT = 1 -> kt = 0
            int kl = (lane >> 4) * 8 + j8;
            int col = ct * 16 + (lane & 15);
            float v = 0.f;
            if (kl < FE_ && col < HN) v = ldsel(Wedge, (size_t)kl * HN + col, f);
            WBedge[i] = (short)f2us(v);
        } else {
            int t = i - tot;
            bpedge[t] = (t < HN) ? ldsel(bedge, t, f) : 0.f;
        }
    }
}

// ---------------- CSR build ----------------
__global__ __launch_bounds__(256) void hist_k(const int* dst, int* cnt, int Ecnt) {
    int e = blockIdx.x * 256 + threadIdx.x;
    if (e < Ecnt) atomicAdd(&cnt[dst[e]], 1);
}

__global__ __launch_bounds__(256) void scan1_k(const int* cnt, int* off, int* part, int Nn) {
    __shared__ int s[256];
    int t = threadIdx.x, i = blockIdx.x * 256 + t;
    int v = (i < Nn) ? cnt[i] : 0;
    s[t] = v; __syncthreads();
    for (int d = 1; d < 256; d <<= 1) {
        int x = (t >= d) ? s[t - d] : 0;
        __syncthreads();
        s[t] += x;
        __syncthreads();
    }
    if (i < Nn) off[i] = s[t] - v;
    if (t == 255) part[blockIdx.x] = s[255];
}

__global__ __launch_bounds__(512) void scan2_k(int* part, int P) {
    __shared__ int s[512];
    int t = threadIdx.x;
    int v = (t < P) ? part[t] : 0;
    s[t] = v; __syncthreads();
    for (int d = 1; d < 512; d <<= 1) {
        int x = (t >= d) ? s[t - d] : 0;
        __syncthreads();
        s[t] += x;
        __syncthreads();
    }
    if (t < P) part[t] = s[t] - v;
}

__global__ __launch_bounds__(256) void scan3_k(const int* part, int* off, int* cursor, int Nn, int Etot) {
    int i = blockIdx.x * 256 + threadIdx.x;
    if (i < Nn) {
        int o = off[i] + part[i >> 8];
        off[i] = o;
        cursor[i] = o;
    }
    if (i == 0) off[Nn] = Etot;
}

__global__ __launch_bounds__(256) void fill_k(
    const int* src, const int* dst, int* cursor, int* srcp, int* eidx, int Ecnt)
{
    int e = blockIdx.x * 256 + threadIdx.x;
    if (e < Ecnt) {
        int p = atomicAdd(&cursor[dst[e]], 1);
        srcp[p] = src[e];
        eidx[p] = e;
    }
}

// ---------------- permute ef rows into CSR order as bf16 ----------------
__global__ __launch_bounds__(256) void permute_k(
    const int* flag, const void* ef, const int* __restrict__ eidx,
    bf16* __restrict__ efp, int Ecnt)
{
    int i = blockIdx.x * 256 + threadIdx.x;
    if (i >= Ecnt) return;
    int e = eidx[i];
    unsigned short row[16];
    if (*flag) {
        const float* er = (const float*)ef + (size_t)e * FE_;
#pragma unroll
        for (int k = 0; k < FE_; k++) row[k] = f2us(er[k]);
    } else {
        const unsigned short* er = (const unsigned short*)ef + (size_t)e * FE_;
#pragma unroll
        for (int k = 0; k < FE_; k++) row[k] = er[k];
    }
    ushort4* o = (ushort4*)(efp + (size_t)i * FE_);
#pragma unroll
    for (int q = 0; q < 4; q++)
        o[q] = ushort4{row[4 * q], row[4 * q + 1], row[4 * q + 2], row[4 * q + 3]};
}

// ---------------- wave-autonomous MFMA-gate message pass (+XCD-bijective block swizzle) ----------------
__global__ __launch_bounds__(256) void msgw_k(
    const bf16* __restrict__ efp, const int* __restrict__ srcp,
    const int* __restrict__ off, const bf16* __restrict__ h,
    const short* __restrict__ WBedge, const float* __restrict__ bpedge,
    bf16* __restrict__ aggb, int Nn)
{
    __shared__ unsigned short gate_s[4][GW][GSTR];
    __shared__ int off_s[4][GW + 4];

    const int tid = threadIdx.x;
    const int w = tid >> 6, lane = tid & 63;
    const int qd = lane >> 4, c0 = lane & 15;

    // XCD-aware bijective swizzle (m204 formula): consecutive HW-dispatched blocks
    // (round-robin across 8 XCDs) -> contiguous dst-node chunk per XCD, so neighbor
    // blocks share L2-resident h panels. Pure permutation: speed-only.
    const int nwg = (int)gridDim.x;
    const int qq = nwg >> 3, rr = nwg & 7;
    const int xcd = (int)blockIdx.x & 7, bi = (int)blockIdx.x >> 3;
    const int wg = (xcd < rr ? xcd * (qq + 1) : rr * (qq + 1) + (xcd - rr) * qq) + bi;

    const int n0w = wg * NPB + w * GW;
    if (n0w >= Nn) return;   // no barriers below -> early exit safe
    const int ltop = (Nn - n0w < GW) ? (Nn - n0w) : GW;

    if (lane <= GW) {
        int idx = n0w + lane;
        if (idx > Nn) idx = Nn;
        off_s[w][lane] = off[idx];
    }

    short8v bfr[CTN];
    float bp[CTN];
#pragma unroll
    for (int ct = 0; ct < CTN; ct++) {
        bfr[ct] = *(const short8v*)(WBedge + ct * 512 + lane * 8);
        bp[ct] = bpedge[ct * 16 + c0];
    }

    const unsigned short* hs = (const unsigned short*)h;
    const int col4 = 4 * lane;
    const int gact = (lane < 50);

    const int w0 = off_s[w][0];
    const int w1 = off_s[w][ltop];
    int cl = 0;
    float a0 = 0.f, a1 = 0.f, a2 = 0.f, a3 = 0.f;

    for (int e0 = w0; e0 < w1; e0 += GW) {
        short8v af = {0, 0, 0, 0, 0, 0, 0, 0};
        if (qd < 2) {
            int er = e0 + c0;
            if (er > EE - 1) er = EE - 1;
            af = __builtin_nontemporal_load(((const short8v*)(efp + (size_t)er * FE_)) + qd);
        }
        const f32x4 zacc = f32x4{0.f, 0.f, 0.f, 0.f};
#pragma unroll
        for (int ct = 0; ct < CTN; ct++) {
            f32x4 c = MFMA16(af, bfr[ct], zacc);
#pragma unroll
            for (int r = 0; r < 4; r++)
                gate_s[w][qd * 4 + r][ct * 16 + c0] = f2us(sigmf(c[r] + bp[ct]));
        }

        int ce = e0 + GW; if (ce > w1) ce = w1;
        while (cl < ltop && off_s[w][cl] < ce) {
            int ns = off_s[w][cl];     if (ns < e0) ns = e0;
            int ne = off_s[w][cl + 1]; if (ne > ce) ne = ce;
            int j = ns;
            for (; j + 4 <= ne; j += 4) {
                int s0 = srcp[j], s1 = srcp[j + 1], s2 = srcp[j + 2], s3 = srcp[j + 3];
                if (gact) {
                    uint2v g0 = *(const uint2v*)&gate_s[w][j     - e0][col4];
                    uint2v g1 = *(const uint2v*)&gate_s[w][j + 1 - e0][col4];
                    uint2v g2 = *(const uint2v*)&gate_s[w][j + 2 - e0][col4];
                    uint2v g3 = *(const uint2v*)&gate_s[w][j + 3 - e0][col4];
                    uint2v h0 = *(const uint2v*)(hs + (size_t)s0 * HN + col4);
                    uint2v h1 = *(const uint2v*)(hs + (size_t)s1 * HN + col4);
                    uint2v h2 = *(const uint2v*)(hs + (size_t)s2 * HN + col4);
                    uint2v h3 = *(const uint2v*)(hs + (size_t)s3 * HN + col4);
                    a0 = fmaf(lo2f(g0[0]), lo2f(h0[0]), a0);
                    a1 = fmaf(hi2f(g0[0]), hi2f(h0[0]), a1);
                    a2 = fmaf(lo2f(g0[1]), lo2f(h0[1]), a2);
                    a3 = fmaf(hi2f(g0[1]), hi2f(h0[1]), a3);
                    a0 = fmaf(lo2f(g1[0]), lo2f(h1[0]), a0);
                    a1 = fmaf(hi2f(g1[0]), hi2f(h1[0]), a1);
                    a2 = fmaf(lo2f(g1[1]), lo2f(h1[1]), a2);
                    a3 = fmaf(hi2f(g1[1]), hi2f(h1[1]), a3);
                    a0 = fmaf(lo2f(g2[0]), lo2f(h2[0]), a0);
                    a1 = fmaf(hi2f(g2[0]), hi2f(h2[0]), a1);
                    a2 = fmaf(lo2f(g2[1]), lo2f(h2[1]), a2);
                    a3 = fmaf(hi2f(g2[1]), hi2f(h2[1]), a3);
                    a0 = fmaf(lo2f(g3[0]), lo2f(h3[0]), a0);
                    a1 = fmaf(hi2f(g3[0]), hi2f(h3[0]), a1);
                    a2 = fmaf(lo2f(g3[1]), lo2f(h3[1]), a2);
                    a3 = fmaf(hi2f(g3[1]), hi2f(h3[1]), a3);
                }
            }
            for (; j < ne; j++) {
                int s = srcp[j];
                if (gact) {
                    uint2v g = *(const uint2v*)&gate_s[w][j - e0][col4];
                    uint2v hv = *(const uint2v*)(hs + (size_t)s * HN + col4);
                    a0 = fmaf(lo2f(g[0]), lo2f(hv[0]), a0);
                    a1 = fmaf(hi2f(g[0]), hi2f(hv[0]), a1);
                    a2 = fmaf(lo2f(g[1]), lo2f(hv[1]), a2);
                    a3 = fmaf(hi2f(g[1]), hi2f(hv[1]), a3);
                }
            }
            if (off_s[w][cl + 1] <= ce) {
                if (gact) {
                    ushort4 o = ushort4{f2us(a0), f2us(a1), f2us(a2), f2us(a3)};
                    *(ushort4*)((unsigned short*)aggb + (size_t)(n0w + cl) * HN + col4) = o;
                }
                a0 = a1 = a2 = a3 = 0.f;
                cl++;
            } else break;
        }
    }

    while (cl < ltop) {
        if (gact) {
            ushort4 o = ushort4{f2us(a0), f2us(a1), f2us(a2), f2us(a3)};
            *(ushort4*)((unsigned short*)aggb + (size_t)(n0w + cl) * HN + col4) = o;
        }
        a0 = a1 = a2 = a3 = 0.f;
        cl++;
    }
}

// ---------------- generic MFMA GEMM (+optional fused score col 200) ----------------
// act: 0 = none, 1 = relu, 2 = sigmoid
__global__ __launch_bounds__(128) void gemmm_k(
    const int* flag, int xmode, const void* X, int K, int xstride, int KT,
    const short* __restrict__ WBp, const float* __restrict__ bp, int act,
    bf16* __restrict__ out, int ostride, float* __restrict__ scoreOut, int Nn)
{
    __shared__ unsigned short Xs[32][232];
    const int tid = threadIdx.x;
    const int w = tid >> 6, lane = tid & 63;
    const int qd = lane >> 4, c0 = lane & 15;
    const int n0 = blockIdx.x * 32;
    const int xf32 = (xmode == 2) ? *flag : xmode;
    const int chunks = (KT * 32) >> 2;

    for (int i = tid; i < 32 * chunks; i += 128) {
        int row = i / chunks, c4 = (i - row * chunks) << 2;
        int grow = n0 + row;
        ushort4 v = ushort4{0, 0, 0, 0};
        if (grow < Nn && c4 < K) {
            if (xf32) {
                const float* xr = (const float*)X + (size_t)grow * xstride + c4;
                float4 fv = *(const float4*)xr;
                v = ushort4{f2us(fv.x), f2us(fv.y), f2us(fv.z), f2us(fv.w)};
            } else {
                v = *(const ushort4*)((const bf16*)X + (size_t)grow * xstride + c4);
            }
        }
        *(ushort4*)&Xs[row][c4] = v;
    }
    __syncthreads();

    const int ct0 = w * 7;
    const int ctn = w ? (CTN - 7) : 7;
    f32x4 acc[2][7];
#pragma unroll
    for (int mt = 0; mt < 2; mt++)
#pragma unroll
        for (int ctl = 0; ctl < 7; ctl++)
            acc[mt][ctl] = f32x4{0.f, 0.f, 0.f, 0.f};

    for (int kt = 0; kt < KT; kt++) {
        short8v a0 = *(const short8v*)&Xs[c0][kt * 32 + qd * 8];
        short8v a1 = *(const short8v*)&Xs[16 + c0][kt * 32 + qd * 8];
        const short* wp = WBp + ((size_t)kt * CTN + ct0) * 512 + lane * 8;
#pragma unroll
        for (int ctl = 0; ctl < 7; ctl++) {
            if (ctl < ctn) {
                short8v b = *(const short8v*)(wp + (size_t)ctl * 512);
                acc[0][ctl] = MFMA16(a0, b, acc[0][ctl]);
                acc[1][ctl] = MFMA16(a1, b, acc[1][ctl]);
            }
        }
    }

#pragma unroll
    for (int mt = 0; mt < 2; mt++)
#pragma unroll
        for (int ctl = 0; ctl < 7; ctl++) {
            if (ctl < ctn) {
#pragma unroll
                for (int r = 0; r < 4; r++) {
                    int row = n0 + mt * 16 + qd * 4 + r;
                    int col = (ct0 + ctl) * 16 + c0;
                    if (row < Nn) {
                        if (col < HN) {
                            float v = acc[mt][ctl][r] + bp[col];
                            if (act == 1) v = fmaxf(v, 0.f);
                            else if (act == 2) v = sigmf(v);
                            out[(size_t)row * ostride + col] = __float2bfloat16(v);
                        } else if (col == HN && scoreOut) {
                            scoreOut[row] = acc[mt][ctl][r] + bp[HN];
                        }
                    }
                }
            }
        }
}

// ---------------- fused MFMA tower-mix + GRU v4: weight-prefetch pipeline (round-6 proven) ----------------
__global__ __launch_bounds__(512) void gru3_k(
    const bf16* __restrict__ aggb, bf16* __restrict__ h,
    const short* __restrict__ WB, const float* __restrict__ bpack,
    const short* __restrict__ WBmix, const float* __restrict__ bpmix, int Nn)
{
    __shared__ unsigned short Xs[MB3][XSTR];   // [m-slot 0..223 | h-slot 224..447]
    const int tid = threadIdx.x;
    const int w = tid >> 6, lane = tid & 63;
    const int qd = lane >> 4, c0 = lane & 15;
    const int n0 = blockIdx.x * MB3;

    // stage agg -> m-slot (nontemporal: read-once stream), h -> h-slot (cached)
    for (int i = tid; i < MB3 * (XSTR / 4); i += 512) {
        int row = i / (XSTR / 4);
        int c4 = (i - row * (XSTR / 4)) * 4;
        int grow = n0 + row;
        uint2v v = uint2v{0u, 0u};
        if (grow < Nn) {
            if (c4 < HN)
                v = __builtin_nontemporal_load((const uint2v*)&aggb[(size_t)grow * HN + c4]);
            else if (c4 >= 224 && c4 < 224 + HN)
                v = *(const uint2v*)&h[(size_t)grow * HN + (c4 - 224)];
        }
        *(uint2v*)&Xs[row][c4] = v;
    }

    // ---- phase-0 weight prefetch for kt=0 (global, independent of LDS: issue pre-barrier)
    const int c0a = (w < 13) ? w : 12;               // j=0 tile (clamped, unused if >=13)
    const int c0b = (8 + w < 13) ? 8 + w : 12;       // j=1 tile
    short8v b0c0, b0c1, b0n0, b0n1;
    b0c0 = *(const short8v*)(WBmix + (size_t)c0a * 512 + lane * 8);
    b0c1 = *(const short8v*)(WBmix + (size_t)c0b * 512 + lane * 8);
    __syncthreads();

    f32x4 acc[4][5];
    short8v a[4];

    // ---- phase 0: m = relu(agg @ W_eff + b_mix); tiles c = 8j+w < 13 (j<2) ----
#pragma unroll
    for (int mt = 0; mt < 4; mt++)
#pragma unroll
        for (int j = 0; j < 2; j++) acc[mt][j] = f32x4{0.f, 0.f, 0.f, 0.f};
    for (int kt = 0; kt < 7; kt++) {
        int ktn = (kt < 6) ? kt + 1 : 6;
        b0n0 = *(const short8v*)(WBmix + ((size_t)ktn * CTN + c0a) * 512 + lane * 8);
        b0n1 = *(const short8v*)(WBmix + ((size_t)ktn * CTN + c0b) * 512 + lane * 8);
#pragma unroll
        for (int mt = 0; mt < 4; mt++)
            a[mt] = *(const short8v*)&Xs[mt * 16 + c0][kt * 32 + qd * 8];
        if (w < 13) {
#pragma unroll
            for (int mt = 0; mt < 4; mt++) acc[mt][0] = MFMA16(a[mt], b0c0, acc[mt][0]);
        }
        if (8 + w < 13) {
#pragma unroll
            for (int mt = 0; mt < 4; mt++) acc[mt][1] = MFMA16(a[mt], b0c1, acc[mt][1]);
        }
        b0c0 = b0n0; b0c1 = b0n1;
    }

    // ---- phase-1 bases + kt=0 weight prefetch (issued before m-write barriers) ----
    const short* wbase[5];
    int cdx[5], gdx[5];
    short8v b1c[5], b1n[5];
#pragma unroll
    for (int j = 0; j < 5; j++) {
        int c = 8 * j + w;
        cdx[j] = c;
        int g = (c < 13) ? 0 : (c < 26) ? 1 : 2;
        gdx[j] = g;
        int ctl = c - g * 13;
        if (ctl > 12) ctl = 12;   // degenerate c=39 wave: clamp (loads unused)
        wbase[j] = WB + ((size_t)(g * KTN) * CTN + ctl) * 512 + lane * 8;
        b1c[j] = *(const short8v*)(wbase[j]);    // kt=0
    }
    __syncthreads();   // all phase-0 reads of m-slot done

    // write m (bf16) directly into m-slot; pads 200..223 stay 0 from staging
#pragma unroll
    for (int j = 0; j < 2; j++) {
        int c = 8 * j + w;
        if (c < 13) {
#pragma unroll
            for (int mt = 0; mt < 4; mt++)
#pragma unroll
                for (int r = 0; r < 4; r++) {
                    int row = mt * 16 + qd * 4 + r;
                    int col = c * 16 + c0;
                    if (col < HN)
                        Xs[row][col] = f2us(fmaxf(acc[mt][j][r] + bpmix[col], 0.f));
                }
        }
    }
    __syncthreads();

    // ---- phase 1: [z|r|q] = [m|h] @ [[Wz|Wr|Wh],[Uz|Ur|0]]; q tiles kt<7 only ----
#pragma unroll
    for (int j = 0; j < 5; j++)
#pragma unroll
        for (int mt = 0; mt < 4; mt++) acc[mt][j] = f32x4{0.f, 0.f, 0.f, 0.f};

    for (int kt = 0; kt < KTN; kt++) {
        int ktn = (kt + 1 < KTN) ? kt + 1 : kt;
#pragma unroll
        for (int j = 0; j < 5; j++) {
            if (gdx[j] < 2 || ktn < 7)    // wave-uniform: prefetch only if next iter uses it
                b1n[j] = *(const short8v*)(wbase[j] + (size_t)ktn * CTN * 512);
        }
#pragma unroll
        for (int mt = 0; mt < 4; mt++)
            a[mt] = *(const short8v*)&Xs[mt * 16 + c0][kt * 32 + qd * 8];
#pragma unroll
        for (int j = 0; j < 5; j++) {
            if (cdx[j] < 39 && (gdx[j] < 2 || kt < 7)) {
#pragma unroll
                for (int mt = 0; mt < 4; mt++) acc[mt][j] = MFMA16(a[mt], b1c[j], acc[mt][j]);
            }
        }
#pragma unroll
        for (int j = 0; j < 5; j++) b1c[j] = b1n[j];
    }

    // ---- phase-2 bases + kt=7 prefetch (hidden under elementwise + barriers) ----
    const short* w2b[5];
    int act2[5];
    short8v b2c[5], b2n[5];
#pragma unroll
    for (int j = 0; j < 5; j++) {
        int c = cdx[j];
        act2[j] = (c >= 26 && c < 39);
        int ctl = act2[j] ? (c - 26) : 0;
        w2b[j] = WB + ((size_t)(2 * KTN + 7) * CTN + ctl) * 512 + lane * 8;
        if (act2[j]) b2c[j] = *(const short8v*)(w2b[j]);
    }
    __syncthreads();   // all phase-1 reads done

    // elementwise: z -> m-slot (bf16); r -> h-slot := bf16(r*h); q stays in regs
#pragma unroll
    for (int j = 0; j < 5; j++) {
        int c = cdx[j];
        if (c < 13) {
#pragma unroll
            for (int mt = 0; mt < 4; mt++)
#pragma unroll
                for (int r = 0; r < 4; r++) {
                    int row = mt * 16 + qd * 4 + r;
                    int col = c * 16 + c0;
                    if (col < HN)
                        Xs[row][col] = f2us(sigmf(acc[mt][j][r] + bpack[col]));
                }
        } else if (c < 26) {
            int ctl = c - 13;
#pragma unroll
            for (int mt = 0; mt < 4; mt++)
#pragma unroll
                for (int r = 0; r < 4; r++) {
                    int row = mt * 16 + qd * 4 + r;
                    int col = ctl * 16 + c0;
                    float rr = sigmf(acc[mt][j][r] + bpack[208 + col]);
                    float hv = us2f(Xs[row][224 + col]);
                    Xs[row][224 + col] = f2us(rr * hv);   // pads: hv=0 -> writes 0, safe
                }
        }
    }
    __syncthreads();   // z + r*h visible

    // ---- phase 2: q += (r*h) @ Uh (kt 7..13 of g=2 pack) ----
    for (int kt = 7; kt < KTN; kt++) {
#pragma unroll
        for (int j = 0; j < 5; j++) {
            if (act2[j] && kt < KTN - 1)
                b2n[j] = *(const short8v*)(w2b[j] + (size_t)(kt + 1 - 7) * CTN * 512);
        }
#pragma unroll
        for (int mt = 0; mt < 4; mt++)
            a[mt] = *(const short8v*)&Xs[mt * 16 + c0][kt * 32 + qd * 8];
#pragma unroll
        for (int j = 0; j < 5; j++) {
            if (act2[j]) {
#pragma unroll
                for (int mt = 0; mt < 4; mt++) acc[mt][j] = MFMA16(a[mt], b2c[j], acc[mt][j]);
            }
        }
#pragma unroll
        for (int j = 0; j < 5; j++) { if (act2[j]) b2c[j] = b2n[j]; }
    }

    // epilogue: h = h + z*(tanh(q + bh) - h), z from m-slot
#pragma unroll
    for (int j = 0; j < 5; j++) {
        int c = cdx[j];
        if (c >= 26 && c < 39) {
            int ctl = c - 26;
#pragma unroll
            for (int mt = 0; mt < 4; mt++)
#pragma unroll
                for (int r = 0; r < 4; r++) {
                    int row = mt * 16 + qd * 4 + r;
                    int col = ctl * 16 + c0;
                    int grow = n0 + row;
                    if (col < HN && grow < Nn) {
                        float ah = acc[mt][j][r] + bpack[416 + col];
                        ah = fminf(fmaxf(ah, -15.f), 15.f);
                        float e = __expf(2.f * ah);
                        float htl = (e - 1.f) / (e + 1.f);
                        float zv = us2f(Xs[row][col]);
                        size_t idx = (size_t)grow * HN + col;
                        float hv = b2f(h[idx]);
                        h[idx] = __float2bfloat16(fmaf(zv, htl - hv, hv));
                    }
                }
        }
    }
}

// ---------------- segment max ----------------
__global__ __launch_bounds__(256) void gmax_k(
    const float* __restrict__ score, const int* __restrict__ bv,
    unsigned* __restrict__ gmax_u, int Nn)
{
    __shared__ unsigned lm[GG];
    const int tid = threadIdx.x;
    for (int i = tid; i < GG; i += 256) lm[i] = 0u;
    __syncthreads();
    int n = blockIdx.x * 256 + tid;
    if (n < Nn) atomicMax(&lm[bv[n]], ordkey(score[n]));
    __syncthreads();
    for (int i = tid; i < GG; i += 256)
        if (lm[i]) atomicMax(&gmax_u[i], lm[i]);
}

// ---------------- exp + segment sum ----------------
__global__ __launch_bounds__(256) void exsum_k(
    const float* __restrict__ score, const int* __restrict__ bv,
    const unsigned* __restrict__ gmax_u, float* __restrict__ ex,
    float* __restrict__ gsum, int Nn)
{
    __shared__ float ls[GG];
    const int tid = threadIdx.x;
    for (int i = tid; i < GG; i += 256) ls[i] = 0.f;
    __syncthreads();
    int n = blockIdx.x * 256 + tid;
    if (n < Nn) {
        int g = bv[n];
        float e = __expf(score[n] - ordinv(gmax_u[g]));
        ex[n] = e;
        atomicAdd(&ls[g], e);
    }
    __syncthreads();
    for (int i = tid; i < GG; i += 256)
        if (ls[i] != 0.f) atomicAdd(&gsum[i], ls[i]);
}

// ---------------- weighted readout scatter ----------------
__global__ __launch_bounds__(256) void scatter_k(
    const bf16* __restrict__ feat, const float* __restrict__ ex,
    const float* __restrict__ gsum, const int* __restrict__ bv,
    float* __restrict__ gout, int Nn)
{
    const int tid = threadIdx.x;
    if (tid >= HN) return;
    int n0 = blockIdx.x * NRB;
    int lim = Nn - n0; if (lim > NRB) lim = NRB;
    float acc = 0.f;
    int cur = -1;
    float inv = 0.f;
    for (int i = 0; i < lim; i++) {
        int n = n0 + i;
        int g = bv[n];
        if (g != cur) {
            if (cur >= 0) atomicAdd(&gout[cur * HN + tid], acc);
            acc = 0.f;
            cur = g;
            inv = 1.0f / gsum[g];
        }
        acc = fmaf(ex[n] * inv, b2f(feat[(size_t)n * HN + tid]), acc);
    }
    if (cur >= 0) atomicAdd(&gout[cur * HN + tid], acc);
}

// ---------------- readout MLP ----------------
template <typename T, int OUTF32>
__device__ __forceinline__ void final_impl(
    float* r1s, const float* gout,
    const void* Wr1, const void* br1, const void* Wout, const void* bout,
    void* out, int g, int tid)
{
    if (tid < HN) {
        float v = LDR<T>::get(br1, tid);
        for (int k = 0; k < HN; k++) v = fmaf(gout[g * HN + k], LDR<T>::get(Wr1, (size_t)k * HN + tid), v);
        r1s[tid] = (v == v) ? fmaxf(v, 0.f) : v;
    }
    __syncthreads();
    if (tid < 64) {
        float a = 0.f;
        for (int k = tid; k < HN; k += 64) a = fmaf(r1s[k], LDR<T>::get(Wout, k), a);
        for (int off = 32; off; off >>= 1) a += __shfl_down(a, off, 64);
        if (tid == 0) {
            float res = a + LDR<T>::get(bout, 0);
            if (OUTF32) ((float*)out)[g] = res;
            else        ((bf16*)out)[g] = __float2bfloat16(res);
        }
    }
}

__global__ __launch_bounds__(256) void final_k(
    const int* flag, const float* gout,
    const void* Wr1, const void* br1, const void* Wout, const void* bout, void* out)
{
    __shared__ float r1s[HN];
    const int g = blockIdx.x, tid = threadIdx.x;
    if (*flag) final_impl<float, 1>(r1s, gout, Wr1, br1, Wout, bout, out, g, tid);
    else       final_impl<bf16,  0>(r1s, gout, Wr1, br1, Wout, bout, out, g, tid);
}

extern "C" void kernel_launch(void* const* d_in, const int* in_sizes, int n_in,
                              void* d_out, int out_size, void* d_ws, size_t ws_size,
                              hipStream_t stream)
{
    const void* nf      = d_in[0];
    const void* ef      = d_in[1];
    const int*  ei      = (const int*)d_in[2];
    const int*  bv      = (const int*)d_in[3];
    const void* W_in    = d_in[4];
    const void* b_in    = d_in[5];
    const void* W_edge  = d_in[6];
    const void* b_edge  = d_in[7];
    const void* W_tower = d_in[8];
    const void* W_mix   = d_in[9];
    const void* b_mix   = d_in[10];
    const void* Wz      = d_in[11];
    const void* Uz      = d_in[12];
    const void* bz      = d_in[13];
    const void* Wr      = d_in[14];
    const void* Ur      = d_in[15];
    const void* br      = d_in[16];
    const void* Wh      = d_in[17];
    const void* Uh      = d_in[18];
    const void* bh      = d_in[19];
    const void* W_score = d_in[20];
    const void* b_score = d_in[21];
    const void* W_feat  = d_in[22];
    const void* b_feat  = d_in[23];
    const void* W_r1    = d_in[24];
    const void* b_r1    = d_in[25];
    const void* W_out   = d_in[26];
    const void* b_out   = d_in[27];

    const int* src = ei;
    const int* dst = ei + EE;

    // ---- workspace layout (~115 MB) ----
    const size_t NH = (size_t)NN * HN;
    char* p = (char*)d_ws;
    auto take = [&](size_t bytes) { char* r = p; p += (bytes + 15) & ~(size_t)15; return r; };
    bf16*  h      = (bf16*)take(NH * 2);
    bf16*  aggb   = (bf16*)take(NH * 2);        // bf16 agg; feat reuses
    float* score  = (float*)take(NN * 4);
    float* ex     = (float*)take(NN * 4);
    unsigned* gmax_u = (unsigned*)take((GG + GG + GG * HN) * 4);
    float* gsum   = (float*)(gmax_u + GG);
    float* gout   = gsum + GG;
    short* WB     = (short*)take(WBSZ * 2);
    float* bpack  = (float*)take(3 * 208 * 4);
    short* WBmix  = (short*)take(7 * CTN * 512 * 2);
    float* bpmix  = (float*)take(208 * 4);
    short* WBfs   = (short*)take(7 * CTN * 512 * 2);
    float* bpfs   = (float*)take(208 * 4);
    short* WBin   = (short*)take(4 * CTN * 512 * 2);
    float* bpin   = (float*)take(208 * 4);
    float* Wef    = (float*)take(FE_ * HN * 4);
    float* bef    = (float*)take(HN * 4);
    short* WBedge = (short*)take(CTN * 512 * 2);
    float* bpedge = (float*)take(208 * 4);
    int*   cnt    = (int*)take(NN * 4);
    int*   off    = (int*)take((NN + 1) * 4);
    int*   cursor = (int*)take(NN * 4);
    int*   part   = (int*)take(512 * 4);
    int*   srcp   = (int*)take(EE * 4);
    int*   eidx   = (int*)take(EE * 4);
    bf16*  efp    = (bf16*)take((size_t)EE * FE_ * 2);
    int*   flag   = (int*)take(16);

    const dim3 blk(256);
    const int zsmall_n4 = (GG + GG + GG * HN) / 4;

    probe_k<<<dim3(1), blk, 0, stream>>>(nf, W_in, flag);

    pack_all_k<<<dim3((PA_TOT + 255) / 256), blk, 0, stream>>>(
        flag, Wz, Uz, bz, Wr, Ur, br, Wh, Uh, bh,
        W_tower, W_mix, b_mix, W_feat, b_feat, W_score, b_score,
        W_in, b_in, W_edge, b_edge,
        WB, bpack, WBmix, bpmix, WBfs, bpfs, WBin, bpin, Wef, bef,
        WBedge, bpedge);

    // CSR build + ef permute (once per launch)
    zero_k<<<dim3((NN / 4 + 255) / 256), blk, 0, stream>>>((float4*)cnt, NN / 4);
    hist_k<<<dim3(EE / 256), blk, 0, stream>>>(dst, cnt, EE);
    const int SB = (NN + 255) / 256;
    scan1_k<<<dim3(SB), blk, 0, stream>>>(cnt, off, part, NN);
    scan2_k<<<dim3(1), dim3(512), 0, stream>>>(part, SB);
    scan3_k<<<dim3(SB), blk, 0, stream>>>(part, off, cursor, NN, EE);
    fill_k<<<dim3(EE / 256), blk, 0, stream>>>(src, dst, cursor, srcp, eidx, EE);
    permute_k<<<dim3(EE / 256), blk, 0, stream>>>(flag, ef, eidx, efp, EE);

    // h = relu(nf @ W_in + b_in)
    gemmm_k<<<dim3(NN / 32), dim3(128), 0, stream>>>(
        flag, 2, nf, FN_, FN_, 4, WBin, bpin, 1, h, HN, (float*)nullptr, NN);

    for (int s = 0; s < STEPS_; s++) {
        msgw_k<<<dim3((NN + NPB - 1) / NPB), blk, 0, stream>>>(
            efp, srcp, off, h, WBedge, bpedge, aggb, NN);
        gru3_k<<<dim3((NN + MB3 - 1) / MB3), dim3(512), 0, stream>>>(
            aggb, h, WB, bpack, WBmix, bpmix, NN);
    }

    // readout: feat GEMM with fused score column
    zero_k<<<dim3((zsmall_n4 + 255) / 256), blk, 0, stream>>>((float4*)gmax_u, zsmall_n4);
    gemmm_k<<<dim3(NN / 32), dim3(128), 0, stream>>>(
        flag, 0, h, HN, HN, 7, WBfs, bpfs, 0, aggb, HN, score, NN);
    gmax_k<<<dim3((NN + 255) / 256), blk, 0, stream>>>(score, bv, gmax_u, NN);
    exsum_k<<<dim3((NN + 255) / 256), blk, 0, stream>>>(score, bv, gmax_u, ex, gsum, NN);
    scatter_k<<<dim3((NN + NRB - 1) / NRB), blk, 0, stream>>>(aggb, ex, gsum, bv, gout, NN);
    final_k<<<dim3(GG), blk, 0, stream>>>(flag, gout, W_r1, b_r1, W_out, b_out, d_out);
}

// Round 11
// 1522.416 us; speedup vs baseline: 1.0892x; 1.0892x over previous
//
#include <hip/hip_runtime.h>
#include <hip/hip_bf16.h>

typedef __hip_bfloat16 bf16;

#define NN  100000   // nodes
#define EE  800000   // edges
#define FN_ 128      // node feature dim
#define FE_ 16       // edge feature dim
#define HN  200      // hidden dim
#define TT  8        // towers
#define DT_ 25       // per-tower dim
#define GG  64       // graphs
#define STEPS_ 3

#define NPB 64       // dst nodes per msg block (4 waves x GW)
#define GW  16       // dst nodes per wave (wave-autonomous)
#define GSTR 212     // gate_s row stride in shorts
#define NRB 128      // nodes per scatter block

// MFMA geometry
#define MB3  64      // nodes per gru block (4 row-tiles of 16) -- round-6 proven config
#define XSTR 456     // gru LDS X row stride in shorts
#define CTN  13      // col tiles (13*16 = 208 >= 200)
#define KTN  14      // gru k tiles (14*32 = 448 = 224(m) + 224(h))
#define WBSZ (3 * KTN * CTN * 512)   // gru packed weight shorts

// pack_all region sizes
#define PA_A (WBSZ + 3 * 208)
#define PA_B (7 * CTN * 512 + 208)
#define PA_C (7 * CTN * 512 + 208)
#define PA_D (4 * CTN * 512 + 208)
#define PA_E (FE_ * HN + HN)
#define PA_F (CTN * 512 + 208)
#define PA_TOT (PA_A + PA_B + PA_C + PA_D + PA_E + PA_F)

typedef __attribute__((ext_vector_type(8))) short short8v;
typedef __attribute__((ext_vector_type(4))) float f32x4;
typedef __attribute__((ext_vector_type(2))) unsigned int uint2v;
#define MFMA16(a, b, c) __builtin_amdgcn_mfma_f32_16x16x32_bf16(a, b, c, 0, 0, 0)

__device__ __forceinline__ float b2f(bf16 v) { return __bfloat162float(v); }
__device__ __forceinline__ float us2f(unsigned short u) { return __uint_as_float((unsigned)u << 16); }
__device__ __forceinline__ float lo2f(unsigned u) { return __uint_as_float(u << 16); }
__device__ __forceinline__ float hi2f(unsigned u) { return __uint_as_float(u & 0xffff0000u); }
__device__ __forceinline__ unsigned short f2us(float x) { bf16 t = __float2bfloat16(x); return *(unsigned short*)&t; }
__device__ __forceinline__ float sigmf(float x) { return 1.0f / (1.0f + __expf(-x)); }

template <typename T> struct LDR;
template <> struct LDR<bf16> {
    static __device__ __forceinline__ float get(const void* p, size_t i) {
        return __bfloat162float(((const bf16*)p)[i]);
    }
};
template <> struct LDR<float> {
    static __device__ __forceinline__ float get(const void* p, size_t i) {
        return ((const float*)p)[i];
    }
};
__device__ __forceinline__ float ldsel(const void* p, size_t i, int f) {
    return f ? LDR<float>::get(p, i) : LDR<bf16>::get(p, i);
}

__device__ __forceinline__ unsigned ordkey(float x) {
    unsigned b = __float_as_uint(x);
    return b ^ (unsigned)(((int)b >> 31) | (int)0x80000000);
}
__device__ __forceinline__ float ordinv(unsigned u) {
    unsigned b = (u & 0x80000000u) ? (u ^ 0x80000000u) : ~u;
    return __uint_as_float(b);
}

// ---------------- dtype probe ----------------
__global__ __launch_bounds__(256) void probe_k(const void* nf, const void* Win, int* flag) {
    __shared__ int cnt;
    if (threadIdx.x == 0) cnt = 0;
    __syncthreads();
    const unsigned short* a = (const unsigned short*)nf;
    const unsigned short* b = (const unsigned short*)Win;
    int c = 0;
    for (int i = threadIdx.x; i < 2048; i += 256) {
        float x = us2f(a[i]);
        float y = us2f(b[i]);
        if (!(fabsf(x) < 1e3f)) c++;
        if (!(fabsf(y) < 1e3f)) c++;
    }
    atomicAdd(&cnt, c);
    __syncthreads();
    if (threadIdx.x == 0) flag[0] = (cnt >= 8) ? 1 : 0;
}

// ---------------- zero fill ----------------
__global__ __launch_bounds__(256) void zero_k(float4* __restrict__ p, int n4) {
    int i = blockIdx.x * 256 + threadIdx.x;
    if (i < n4) p[i] = float4{0.f, 0.f, 0.f, 0.f};
}

// ---------------- ALL weight packs in one kernel ----------------
__global__ __launch_bounds__(256) void pack_all_k(
    const int* flag,
    const void* Wz, const void* Uz, const void* bz,
    const void* Wr, const void* Ur, const void* br,
    const void* Wh, const void* Uh, const void* bh,
    const void* Wt, const void* Wmix, const void* bmix,
    const void* Wfeat, const void* bfeat, const void* Wscore, const void* bscore,
    const void* Win, const void* bin,
    const void* Wedge, const void* bedge,
    short* __restrict__ WB, float* __restrict__ bpack,
    short* __restrict__ WBmix, float* __restrict__ bpmix,
    short* __restrict__ WBfs, float* __restrict__ bpfs,
    short* __restrict__ WBin, float* __restrict__ bpin,
    float* __restrict__ Wef, float* __restrict__ bef,
    short* __restrict__ WBedge, float* __restrict__ bpedge)
{
    int i = blockIdx.x * 256 + threadIdx.x;
    const int f = *flag;

    if (i < PA_A) {                       // ---- region A: GRU gates [W;U] K=448
        if (i < WBSZ) {
            int j8 = i & 7;
            int e = i >> 3;
            int lane = e & 63; e >>= 6;
            int ct = e % 13; e /= 13;
            int kt = e % 14;
            int g = e / 14;
            int kl = kt * 32 + (lane >> 4) * 8 + j8;
            int col = ct * 16 + (lane & 15);
            int ksrc = (kl < 224) ? kl : kl - 224;
            const void* W = (kl < 224) ? (g == 0 ? Wz : g == 1 ? Wr : Wh)
                                       : (g == 0 ? Uz : g == 1 ? Ur : Uh);
            float v = 0.f;
            if (ksrc < HN && col < HN) v = ldsel(W, (size_t)ksrc * HN + col, f);
            WB[i] = (short)f2us(v);
        } else {
            int t = i - WBSZ;
            int g = t / 208, col = t % 208;
            const void* B = g == 0 ? bz : g == 1 ? br : bh;
            bpack[t] = (col < HN) ? ldsel(B, col, f) : 0.f;
        }
        return;
    }
    i -= PA_A;
    if (i < PA_B) {                       // ---- region B: W_eff = blockdiag(W_tower)@W_mix
        const int tot = 7 * CTN * 512;
        if (i < tot) {
            int j8 = i & 7;
            int e = i >> 3;
            int lane = e & 63; e >>= 6;
            int ct = e % CTN;
            int kt = e / CTN;
            int kl = kt * 32 + (lane >> 4) * 8 + j8;
            int col = ct * 16 + (lane & 15);
            float v = 0.f;
            if (kl < HN && col < HN) {
                int t = kl / DT_, d = kl - t * DT_;
                for (int ee = 0; ee < DT_; ee++) {
                    float wt = ldsel(Wt, (size_t)(t * DT_ + d) * DT_ + ee, f);
                    float wm = ldsel(Wmix, (size_t)(t * DT_ + ee) * HN + col, f);
                    v = fmaf(wt, wm, v);
                }
            }
            WBmix[i] = (short)f2us(v);
        } else {
            int t = i - tot;
            bpmix[t] = (t < HN) ? ldsel(bmix, t, f) : 0.f;
        }
        return;
    }
    i -= PA_B;
    if (i < PA_C) {                       // ---- region C: W_feat with W_score as col 200
        const int tot = 7 * CTN * 512;
        if (i < tot) {
            int j8 = i & 7;
            int e = i >> 3;
            int lane = e & 63; e >>= 6;
            int ct = e % CTN;
            int kt = e / CTN;
            int kl = kt * 32 + (lane >> 4) * 8 + j8;
            int col = ct * 16 + (lane & 15);
            float v = 0.f;
            if (kl < HN) {
                if (col < HN) v = ldsel(Wfeat, (size_t)kl * HN + col, f);
                else if (col == HN) v = ldsel(Wscore, kl, f);
            }
            WBfs[i] = (short)f2us(v);
        } else {
            int t = i - tot;
            float v = 0.f;
            if (t < HN) v = ldsel(bfeat, t, f);
            else if (t == HN) v = ldsel(bscore, 0, f);
            bpfs[t] = v;
        }
        return;
    }
    i -= PA_C;
    if (i < PA_D) {                       // ---- region D: W_in (K=128)
        const int tot = 4 * CTN * 512;
        if (i < tot) {
            int j8 = i & 7;
            int e = i >> 3;
            int lane = e & 63; e >>= 6;
            int ct = e % CTN;
            int kt = e / CTN;
            int kl = kt * 32 + (lane >> 4) * 8 + j8;
            int col = ct * 16 + (lane & 15);
            float v = 0.f;
            if (kl < FN_ && col < HN) v = ldsel(Win, (size_t)kl * HN + col, f);
            WBin[i] = (short)f2us(v);
        } else {
            int t = i - tot;
            bpin[t] = (t < HN) ? ldsel(bin, t, f) : 0.f;
        }
        return;
    }
    i -= PA_D;
    if (i < PA_E) {                       // ---- region E: W_edge as f32 + b_edge (legacy)
        if (i < FE_ * HN) Wef[i] = ldsel(Wedge, i, f);
        else bef[i - FE_ * HN] = ldsel(bedge, i - FE_ * HN, f);
        return;
    }
    i -= PA_E;
    if (i < PA_F) {                       // ---- region F: W_edge MFMA pack (KT=1, K=16 padded to 32)
        const int tot = CTN * 512;
        if (i < tot) {
            int j8 = i & 7;
            int e = i >> 3;
            int lane = e & 63; e >>= 6;
            int ct = e;                    // KT = 1 -> kt = 0
            int kl = (lane >> 4) * 8 + j8;
            int col = ct * 16 + (lane & 15);
            float v = 0.f;
            if (kl < FE_ && col < HN) v = ldsel(Wedge, (size_t)kl * HN + col, f);
            WBedge[i] = (short)f2us(v);
        } else {
            int t = i - tot;
            bpedge[t] = (t < HN) ? ldsel(bedge, t, f) : 0.f;
        }
    }
}

// ---------------- CSR build ----------------
__global__ __launch_bounds__(256) void hist_k(const int* dst, int* cnt, int Ecnt) {
    int e = blockIdx.x * 256 + threadIdx.x;
    if (e < Ecnt) atomicAdd(&cnt[dst[e]], 1);
}

__global__ __launch_bounds__(256) void scan1_k(const int* cnt, int* off, int* part, int Nn) {
    __shared__ int s[256];
    int t = threadIdx.x, i = blockIdx.x * 256 + t;
    int v = (i < Nn) ? cnt[i] : 0;
    s[t] = v; __syncthreads();
    for (int d = 1; d < 256; d <<= 1) {
        int x = (t >= d) ? s[t - d] : 0;
        __syncthreads();
        s[t] += x;
        __syncthreads();
    }
    if (i < Nn) off[i] = s[t] - v;
    if (t == 255) part[blockIdx.x] = s[255];
}

__global__ __launch_bounds__(512) void scan2_k(int* part, int P) {
    __shared__ int s[512];
    int t = threadIdx.x;
    int v = (t < P) ? part[t] : 0;
    s[t] = v; __syncthreads();
    for (int d = 1; d < 512; d <<= 1) {
        int x = (t >= d) ? s[t - d] : 0;
        __syncthreads();
        s[t] += x;
        __syncthreads();
    }
    if (t < P) part[t] = s[t] - v;
}

__global__ __launch_bounds__(256) void scan3_k(const int* part, int* off, int* cursor, int Nn, int Etot) {
    int i = blockIdx.x * 256 + threadIdx.x;
    if (i < Nn) {
        int o = off[i] + part[i >> 8];
        off[i] = o;
        cursor[i] = o;
    }
    if (i == 0) off[Nn] = Etot;
}

__global__ __launch_bounds__(256) void fill_k(
    const int* src, const int* dst, int* cursor, int* srcp, int* eidx, int Ecnt)
{
    int e = blockIdx.x * 256 + threadIdx.x;
    if (e < Ecnt) {
        int p = atomicAdd(&cursor[dst[e]], 1);
        srcp[p] = src[e];
        eidx[p] = e;
    }
}

// ---------------- permute ef rows into CSR order as bf16 ----------------
__global__ __launch_bounds__(256) void permute_k(
    const int* flag, const void* ef, const int* __restrict__ eidx,
    bf16* __restrict__ efp, int Ecnt)
{
    int i = blockIdx.x * 256 + threadIdx.x;
    if (i >= Ecnt) return;
    int e = eidx[i];
    unsigned short row[16];
    if (*flag) {
        const float* er = (const float*)ef + (size_t)e * FE_;
#pragma unroll
        for (int k = 0; k < FE_; k++) row[k] = f2us(er[k]);
    } else {
        const unsigned short* er = (const unsigned short*)ef + (size_t)e * FE_;
#pragma unroll
        for (int k = 0; k < FE_; k++) row[k] = er[k];
    }
    ushort4* o = (ushort4*)(efp + (size_t)i * FE_);
#pragma unroll
    for (int q = 0; q < 4; q++)
        o[q] = ushort4{row[4 * q], row[4 * q + 1], row[4 * q + 2], row[4 * q + 3]};
}

// ---------------- wave-autonomous MFMA-gate message pass v2: srcp staged in LDS ----------------
// Fix for the two-hop dependent chain: the chunk's 16 srcp values are loaded from
// global BEFORE the gate-MFMA phase (latency hidden under ~800cy of MFMA+sigmoid),
// parked in wave-private LDS, and phase B reads them via cheap ds_read.
__global__ __launch_bounds__(256) void msgw_k(
    const bf16* __restrict__ efp, const int* __restrict__ srcp,
    const int* __restrict__ off, const bf16* __restrict__ h,
    const short* __restrict__ WBedge, const float* __restrict__ bpedge,
    bf16* __restrict__ aggb, int Nn)
{
    __shared__ unsigned short gate_s[4][GW][GSTR];
    __shared__ int off_s[4][GW + 4];
    __shared__ int srcp_s[4][GW];

    const int tid = threadIdx.x;
    const int w = tid >> 6, lane = tid & 63;
    const int qd = lane >> 4, c0 = lane & 15;
    const int n0w = blockIdx.x * NPB + w * GW;
    if (n0w >= Nn) return;   // no barriers below -> early exit safe
    const int ltop = (Nn - n0w < GW) ? (Nn - n0w) : GW;

    if (lane <= GW) {
        int idx = n0w + lane;
        if (idx > Nn) idx = Nn;
        off_s[w][lane] = off[idx];
    }

    short8v bfr[CTN];
    float bp[CTN];
#pragma unroll
    for (int ct = 0; ct < CTN; ct++) {
        bfr[ct] = *(const short8v*)(WBedge + ct * 512 + lane * 8);
        bp[ct] = bpedge[ct * 16 + c0];
    }

    const unsigned short* hs = (const unsigned short*)h;
    const int col4 = 4 * lane;
    const int gact = (lane < 50);

    const int w0 = off_s[w][0];
    const int w1 = off_s[w][ltop];
    int cl = 0;
    float a0 = 0.f, a1 = 0.f, a2 = 0.f, a3 = 0.f;

    for (int e0 = w0; e0 < w1; e0 += GW) {
        // ---- stage this chunk's srcp (global load issued BEFORE gate MFMA phase;
        //      its latency hides under the MFMA+sigmoid work below)
        if (lane < GW) {
            int ii = e0 + lane;
            if (ii > w1 - 1) ii = w1 - 1;   // clamp; entries >= w1-e0 unused
            srcp_s[w][lane] = srcp[ii];
        }

        // ---- phase A: gates for edges [e0, e0+16) (this wave only) ----
        short8v af = {0, 0, 0, 0, 0, 0, 0, 0};
        if (qd < 2) {
            int er = e0 + c0;
            if (er > EE - 1) er = EE - 1;
            af = __builtin_nontemporal_load(((const short8v*)(efp + (size_t)er * FE_)) + qd);
        }
        const f32x4 zacc = f32x4{0.f, 0.f, 0.f, 0.f};
#pragma unroll
        for (int ct = 0; ct < CTN; ct++) {
            f32x4 c = MFMA16(af, bfr[ct], zacc);
#pragma unroll
            for (int r = 0; r < 4; r++)
                gate_s[w][qd * 4 + r][ct * 16 + c0] = f2us(sigmf(c[r] + bp[ct]));
        }

        // ---- phase B: gather; srcp from LDS (one global hop per edge, not two) ----
        int ce = e0 + GW; if (ce > w1) ce = w1;
        while (cl < ltop && off_s[w][cl] < ce) {
            int ns = off_s[w][cl];     if (ns < e0) ns = e0;
            int ne = off_s[w][cl + 1]; if (ne > ce) ne = ce;
            int j = ns;
            for (; j + 4 <= ne; j += 4) {
                int s0 = srcp_s[w][j     - e0];
                int s1 = srcp_s[w][j + 1 - e0];
                int s2 = srcp_s[w][j + 2 - e0];
                int s3 = srcp_s[w][j + 3 - e0];
                if (gact) {
                    uint2v g0 = *(const uint2v*)&gate_s[w][j     - e0][col4];
                    uint2v g1 = *(const uint2v*)&gate_s[w][j + 1 - e0][col4];
                    uint2v g2 = *(const uint2v*)&gate_s[w][j + 2 - e0][col4];
                    uint2v g3 = *(const uint2v*)&gate_s[w][j + 3 - e0][col4];
                    uint2v h0 = *(const uint2v*)(hs + (size_t)s0 * HN + col4);
                    uint2v h1 = *(const uint2v*)(hs + (size_t)s1 * HN + col4);
                    uint2v h2 = *(const uint2v*)(hs + (size_t)s2 * HN + col4);
                    uint2v h3 = *(const uint2v*)(hs + (size_t)s3 * HN + col4);
                    a0 = fmaf(lo2f(g0[0]), lo2f(h0[0]), a0);
                    a1 = fmaf(hi2f(g0[0]), hi2f(h0[0]), a1);
                    a2 = fmaf(lo2f(g0[1]), lo2f(h0[1]), a2);
                    a3 = fmaf(hi2f(g0[1]), hi2f(h0[1]), a3);
                    a0 = fmaf(lo2f(g1[0]), lo2f(h1[0]), a0);
                    a1 = fmaf(hi2f(g1[0]), hi2f(h1[0]), a1);
                    a2 = fmaf(lo2f(g1[1]), lo2f(h1[1]), a2);
                    a3 = fmaf(hi2f(g1[1]), hi2f(h1[1]), a3);
                    a0 = fmaf(lo2f(g2[0]), lo2f(h2[0]), a0);
                    a1 = fmaf(hi2f(g2[0]), hi2f(h2[0]), a1);
                    a2 = fmaf(lo2f(g2[1]), lo2f(h2[1]), a2);
                    a3 = fmaf(hi2f(g2[1]), hi2f(h2[1]), a3);
                    a0 = fmaf(lo2f(g3[0]), lo2f(h3[0]), a0);
                    a1 = fmaf(hi2f(g3[0]), hi2f(h3[0]), a1);
                    a2 = fmaf(lo2f(g3[1]), lo2f(h3[1]), a2);
                    a3 = fmaf(hi2f(g3[1]), hi2f(h3[1]), a3);
                }
            }
            for (; j < ne; j++) {
                int s = srcp_s[w][j - e0];
                if (gact) {
                    uint2v g = *(const uint2v*)&gate_s[w][j - e0][col4];
                    uint2v hv = *(const uint2v*)(hs + (size_t)s * HN + col4);
                    a0 = fmaf(lo2f(g[0]), lo2f(hv[0]), a0);
                    a1 = fmaf(hi2f(g[0]), hi2f(hv[0]), a1);
                    a2 = fmaf(lo2f(g[1]), lo2f(hv[1]), a2);
                    a3 = fmaf(hi2f(g[1]), hi2f(hv[1]), a3);
                }
            }
            if (off_s[w][cl + 1] <= ce) {
                if (gact) {
                    ushort4 o = ushort4{f2us(a0), f2us(a1), f2us(a2), f2us(a3)};
                    *(ushort4*)((unsigned short*)aggb + (size_t)(n0w + cl) * HN + col4) = o;
                }
                a0 = a1 = a2 = a3 = 0.f;
                cl++;
            } else break;
        }
    }

    while (cl < ltop) {
        if (gact) {
            ushort4 o = ushort4{f2us(a0), f2us(a1), f2us(a2), f2us(a3)};
            *(ushort4*)((unsigned short*)aggb + (size_t)(n0w + cl) * HN + col4) = o;
        }
        a0 = a1 = a2 = a3 = 0.f;
        cl++;
    }
}

// ---------------- generic MFMA GEMM (+optional fused score col 200) ----------------
// act: 0 = none, 1 = relu, 2 = sigmoid
__global__ __launch_bounds__(128) void gemmm_k(
    const int* flag, int xmode, const void* X, int K, int xstride, int KT,
    const short* __restrict__ WBp, const float* __restrict__ bp, int act,
    bf16* __restrict__ out, int ostride, float* __restrict__ scoreOut, int Nn)
{
    __shared__ unsigned short Xs[32][232];
    const int tid = threadIdx.x;
    const int w = tid >> 6, lane = tid & 63;
    const int qd = lane >> 4, c0 = lane & 15;
    const int n0 = blockIdx.x * 32;
    const int xf32 = (xmode == 2) ? *flag : xmode;
    const int chunks = (KT * 32) >> 2;

    for (int i = tid; i < 32 * chunks; i += 128) {
        int row = i / chunks, c4 = (i - row * chunks) << 2;
        int grow = n0 + row;
        ushort4 v = ushort4{0, 0, 0, 0};
        if (grow < Nn && c4 < K) {
            if (xf32) {
                const float* xr = (const float*)X + (size_t)grow * xstride + c4;
                float4 fv = *(const float4*)xr;
                v = ushort4{f2us(fv.x), f2us(fv.y), f2us(fv.z), f2us(fv.w)};
            } else {
                v = *(const ushort4*)((const bf16*)X + (size_t)grow * xstride + c4);
            }
        }
        *(ushort4*)&Xs[row][c4] = v;
    }
    __syncthreads();

    const int ct0 = w * 7;
    const int ctn = w ? (CTN - 7) : 7;
    f32x4 acc[2][7];
#pragma unroll
    for (int mt = 0; mt < 2; mt++)
#pragma unroll
        for (int ctl = 0; ctl < 7; ctl++)
            acc[mt][ctl] = f32x4{0.f, 0.f, 0.f, 0.f};

    for (int kt = 0; kt < KT; kt++) {
        short8v a0 = *(const short8v*)&Xs[c0][kt * 32 + qd * 8];
        short8v a1 = *(const short8v*)&Xs[16 + c0][kt * 32 + qd * 8];
        const short* wp = WBp + ((size_t)kt * CTN + ct0) * 512 + lane * 8;
#pragma unroll
        for (int ctl = 0; ctl < 7; ctl++) {
            if (ctl < ctn) {
                short8v b = *(const short8v*)(wp + (size_t)ctl * 512);
                acc[0][ctl] = MFMA16(a0, b, acc[0][ctl]);
                acc[1][ctl] = MFMA16(a1, b, acc[1][ctl]);
            }
        }
    }

#pragma unroll
    for (int mt = 0; mt < 2; mt++)
#pragma unroll
        for (int ctl = 0; ctl < 7; ctl++) {
            if (ctl < ctn) {
#pragma unroll
                for (int r = 0; r < 4; r++) {
                    int row = n0 + mt * 16 + qd * 4 + r;
                    int col = (ct0 + ctl) * 16 + c0;
                    if (row < Nn) {
                        if (col < HN) {
                            float v = acc[mt][ctl][r] + bp[col];
                            if (act == 1) v = fmaxf(v, 0.f);
                            else if (act == 2) v = sigmf(v);
                            out[(size_t)row * ostride + col] = __float2bfloat16(v);
                        } else if (col == HN && scoreOut) {
                            scoreOut[row] = acc[mt][ctl][r] + bp[HN];
                        }
                    }
                }
            }
        }
}

// ---------------- fused MFMA tower-mix + GRU v4: weight-prefetch pipeline (round-6 proven) ----------------
__global__ __launch_bounds__(512) void gru3_k(
    const bf16* __restrict__ aggb, bf16* __restrict__ h,
    const short* __restrict__ WB, const float* __restrict__ bpack,
    const short* __restrict__ WBmix, const float* __restrict__ bpmix, int Nn)
{
    __shared__ unsigned short Xs[MB3][XSTR];   // [m-slot 0..223 | h-slot 224..447]
    const int tid = threadIdx.x;
    const int w = tid >> 6, lane = tid & 63;
    const int qd = lane >> 4, c0 = lane & 15;
    const int n0 = blockIdx.x * MB3;

    // stage agg -> m-slot (nontemporal: read-once stream), h -> h-slot (cached)
    for (int i = tid; i < MB3 * (XSTR / 4); i += 512) {
        int row = i / (XSTR / 4);
        int c4 = (i - row * (XSTR / 4)) * 4;
        int grow = n0 + row;
        uint2v v = uint2v{0u, 0u};
        if (grow < Nn) {
            if (c4 < HN)
                v = __builtin_nontemporal_load((const uint2v*)&aggb[(size_t)grow * HN + c4]);
            else if (c4 >= 224 && c4 < 224 + HN)
                v = *(const uint2v*)&h[(size_t)grow * HN + (c4 - 224)];
        }
        *(uint2v*)&Xs[row][c4] = v;
    }

    // ---- phase-0 weight prefetch for kt=0 (global, independent of LDS: issue pre-barrier)
    const int c0a = (w < 13) ? w : 12;               // j=0 tile (clamped, unused if >=13)
    const int c0b = (8 + w < 13) ? 8 + w : 12;       // j=1 tile
    short8v b0c0, b0c1, b0n0, b0n1;
    b0c0 = *(const short8v*)(WBmix + (size_t)c0a * 512 + lane * 8);
    b0c1 = *(const short8v*)(WBmix + (size_t)c0b * 512 + lane * 8);
    __syncthreads();

    f32x4 acc[4][5];
    short8v a[4];

    // ---- phase 0: m = relu(agg @ W_eff + b_mix); tiles c = 8j+w < 13 (j<2) ----
#pragma unroll
    for (int mt = 0; mt < 4; mt++)
#pragma unroll
        for (int j = 0; j < 2; j++) acc[mt][j] = f32x4{0.f, 0.f, 0.f, 0.f};
    for (int kt = 0; kt < 7; kt++) {
        int ktn = (kt < 6) ? kt + 1 : 6;
        b0n0 = *(const short8v*)(WBmix + ((size_t)ktn * CTN + c0a) * 512 + lane * 8);
        b0n1 = *(const short8v*)(WBmix + ((size_t)ktn * CTN + c0b) * 512 + lane * 8);
#pragma unroll
        for (int mt = 0; mt < 4; mt++)
            a[mt] = *(const short8v*)&Xs[mt * 16 + c0][kt * 32 + qd * 8];
        if (w < 13) {
#pragma unroll
            for (int mt = 0; mt < 4; mt++) acc[mt][0] = MFMA16(a[mt], b0c0, acc[mt][0]);
        }
        if (8 + w < 13) {
#pragma unroll
            for (int mt = 0; mt < 4; mt++) acc[mt][1] = MFMA16(a[mt], b0c1, acc[mt][1]);
        }
        b0c0 = b0n0; b0c1 = b0n1;
    }

    // ---- phase-1 bases + kt=0 weight prefetch (issued before m-write barriers) ----
    const short* wbase[5];
    int cdx[5], gdx[5];
    short8v b1c[5], b1n[5];
#pragma unroll
    for (int j = 0; j < 5; j++) {
        int c = 8 * j + w;
        cdx[j] = c;
        int g = (c < 13) ? 0 : (c < 26) ? 1 : 2;
        gdx[j] = g;
        int ctl = c - g * 13;
        if (ctl > 12) ctl = 12;   // degenerate c=39 wave: clamp (loads unused)
        wbase[j] = WB + ((size_t)(g * KTN) * CTN + ctl) * 512 + lane * 8;
        b1c[j] = *(const short8v*)(wbase[j]);    // kt=0
    }
    __syncthreads();   // all phase-0 reads of m-slot done

    // write m (bf16) directly into m-slot; pads 200..223 stay 0 from staging
#pragma unroll
    for (int j = 0; j < 2; j++) {
        int c = 8 * j + w;
        if (c < 13) {
#pragma unroll
            for (int mt = 0; mt < 4; mt++)
#pragma unroll
                for (int r = 0; r < 4; r++) {
                    int row = mt * 16 + qd * 4 + r;
                    int col = c * 16 + c0;
                    if (col < HN)
                        Xs[row][col] = f2us(fmaxf(acc[mt][j][r] + bpmix[col], 0.f));
                }
        }
    }
    __syncthreads();

    // ---- phase 1: [z|r|q] = [m|h] @ [[Wz|Wr|Wh],[Uz|Ur|0]]; q tiles kt<7 only ----
#pragma unroll
    for (int j = 0; j < 5; j++)
#pragma unroll
        for (int mt = 0; mt < 4; mt++) acc[mt][j] = f32x4{0.f, 0.f, 0.f, 0.f};

    for (int kt = 0; kt < KTN; kt++) {
        int ktn = (kt + 1 < KTN) ? kt + 1 : kt;
#pragma unroll
        for (int j = 0; j < 5; j++) {
            if (gdx[j] < 2 || ktn < 7)    // wave-uniform: prefetch only if next iter uses it
                b1n[j] = *(const short8v*)(wbase[j] + (size_t)ktn * CTN * 512);
        }
#pragma unroll
        for (int mt = 0; mt < 4; mt++)
            a[mt] = *(const short8v*)&Xs[mt * 16 + c0][kt * 32 + qd * 8];
#pragma unroll
        for (int j = 0; j < 5; j++) {
            if (cdx[j] < 39 && (gdx[j] < 2 || kt < 7)) {
#pragma unroll
                for (int mt = 0; mt < 4; mt++) acc[mt][j] = MFMA16(a[mt], b1c[j], acc[mt][j]);
            }
        }
#pragma unroll
        for (int j = 0; j < 5; j++) b1c[j] = b1n[j];
    }

    // ---- phase-2 bases + kt=7 prefetch (hidden under elementwise + barriers) ----
    const short* w2b[5];
    int act2[5];
    short8v b2c[5], b2n[5];
#pragma unroll
    for (int j = 0; j < 5; j++) {
        int c = cdx[j];
        act2[j] = (c >= 26 && c < 39);
        int ctl = act2[j] ? (c - 26) : 0;
        w2b[j] = WB + ((size_t)(2 * KTN + 7) * CTN + ctl) * 512 + lane * 8;
        if (act2[j]) b2c[j] = *(const short8v*)(w2b[j]);
    }
    __syncthreads();   // all phase-1 reads done

    // elementwise: z -> m-slot (bf16); r -> h-slot := bf16(r*h); q stays in regs
#pragma unroll
    for (int j = 0; j < 5; j++) {
        int c = cdx[j];
        if (c < 13) {
#pragma unroll
            for (int mt = 0; mt < 4; mt++)
#pragma unroll
                for (int r = 0; r < 4; r++) {
                    int row = mt * 16 + qd * 4 + r;
                    int col = c * 16 + c0;
                    if (col < HN)
                        Xs[row][col] = f2us(sigmf(acc[mt][j][r] + bpack[col]));
                }
        } else if (c < 26) {
            int ctl = c - 13;
#pragma unroll
            for (int mt = 0; mt < 4; mt++)
#pragma unroll
                for (int r = 0; r < 4; r++) {
                    int row = mt * 16 + qd * 4 + r;
                    int col = ctl * 16 + c0;
                    float rr = sigmf(acc[mt][j][r] + bpack[208 + col]);
                    float hv = us2f(Xs[row][224 + col]);
                    Xs[row][224 + col] = f2us(rr * hv);   // pads: hv=0 -> writes 0, safe
                }
        }
    }
    __syncthreads();   // z + r*h visible

    // ---- phase 2: q += (r*h) @ Uh (kt 7..13 of g=2 pack) ----
    for (int kt = 7; kt < KTN; kt++) {
#pragma unroll
        for (int j = 0; j < 5; j++) {
            if (act2[j] && kt < KTN - 1)
                b2n[j] = *(const short8v*)(w2b[j] + (size_t)(kt + 1 - 7) * CTN * 512);
        }
#pragma unroll
        for (int mt = 0; mt < 4; mt++)
            a[mt] = *(const short8v*)&Xs[mt * 16 + c0][kt * 32 + qd * 8];
#pragma unroll
        for (int j = 0; j < 5; j++) {
            if (act2[j]) {
#pragma unroll
                for (int mt = 0; mt < 4; mt++) acc[mt][j] = MFMA16(a[mt], b2c[j], acc[mt][j]);
            }
        }
#pragma unroll
        for (int j = 0; j < 5; j++) { if (act2[j]) b2c[j] = b2n[j]; }
    }

    // epilogue: h = h + z*(tanh(q + bh) - h), z from m-slot
#pragma unroll
    for (int j = 0; j < 5; j++) {
        int c = cdx[j];
        if (c >= 26 && c < 39) {
            int ctl = c - 26;
#pragma unroll
            for (int mt = 0; mt < 4; mt++)
#pragma unroll
                for (int r = 0; r < 4; r++) {
                    int row = mt * 16 + qd * 4 + r;
                    int col = ctl * 16 + c0;
                    int grow = n0 + row;
                    if (col < HN && grow < Nn) {
                        float ah = acc[mt][j][r] + bpack[416 + col];
                        ah = fminf(fmaxf(ah, -15.f), 15.f);
                        float e = __expf(2.f * ah);
                        float htl = (e - 1.f) / (e + 1.f);
                        float zv = us2f(Xs[row][col]);
                        size_t idx = (size_t)grow * HN + col;
                        float hv = b2f(h[idx]);
                        h[idx] = __float2bfloat16(fmaf(zv, htl - hv, hv));
                    }
                }
        }
    }
}

// ---------------- segment max ----------------
__global__ __launch_bounds__(256) void gmax_k(
    const float* __restrict__ score, const int* __restrict__ bv,
    unsigned* __restrict__ gmax_u, int Nn)
{
    __shared__ unsigned lm[GG];
    const int tid = threadIdx.x;
    for (int i = tid; i < GG; i += 256) lm[i] = 0u;
    __syncthreads();
    int n = blockIdx.x * 256 + tid;
    if (n < Nn) atomicMax(&lm[bv[n]], ordkey(score[n]));
    __syncthreads();
    for (int i = tid; i < GG; i += 256)
        if (lm[i]) atomicMax(&gmax_u[i], lm[i]);
}

// ---------------- exp + segment sum ----------------
__global__ __launch_bounds__(256) void exsum_k(
    const float* __restrict__ score, const int* __restrict__ bv,
    const unsigned* __restrict__ gmax_u, float* __restrict__ ex,
    float* __restrict__ gsum, int Nn)
{
    __shared__ float ls[GG];
    const int tid = threadIdx.x;
    for (int i = tid; i < GG; i += 256) ls[i] = 0.f;
    __syncthreads();
    int n = blockIdx.x * 256 + tid;
    if (n < Nn) {
        int g = bv[n];
        float e = __expf(score[n] - ordinv(gmax_u[g]));
        ex[n] = e;
        atomicAdd(&ls[g], e);
    }
    __syncthreads();
    for (int i = tid; i < GG; i += 256)
        if (ls[i] != 0.f) atomicAdd(&gsum[i], ls[i]);
}

// ---------------- weighted readout scatter ----------------
__global__ __launch_bounds__(256) void scatter_k(
    const bf16* __restrict__ feat, const float* __restrict__ ex,
    const float* __restrict__ gsum, const int* __restrict__ bv,
    float* __restrict__ gout, int Nn)
{
    const int tid = threadIdx.x;
    if (tid >= HN) return;
    int n0 = blockIdx.x * NRB;
    int lim = Nn - n0; if (lim > NRB) lim = NRB;
    float acc = 0.f;
    int cur = -1;
    float inv = 0.f;
    for (int i = 0; i < lim; i++) {
        int n = n0 + i;
        int g = bv[n];
        if (g != cur) {
            if (cur >= 0) atomicAdd(&gout[cur * HN + tid], acc);
            acc = 0.f;
            cur = g;
            inv = 1.0f / gsum[g];
        }
        acc = fmaf(ex[n] * inv, b2f(feat[(size_t)n * HN + tid]), acc);
    }
    if (cur >= 0) atomicAdd(&gout[cur * HN + tid], acc);
}

// ---------------- readout MLP ----------------
template <typename T, int OUTF32>
__device__ __forceinline__ void final_impl(
    float* r1s, const float* gout,
    const void* Wr1, const void* br1, const void* Wout, const void* bout,
    void* out, int g, int tid)
{
    if (tid < HN) {
        float v = LDR<T>::get(br1, tid);
        for (int k = 0; k < HN; k++) v = fmaf(gout[g * HN + k], LDR<T>::get(Wr1, (size_t)k * HN + tid), v);
        r1s[tid] = (v == v) ? fmaxf(v, 0.f) : v;
    }
    __syncthreads();
    if (tid < 64) {
        float a = 0.f;
        for (int k = tid; k < HN; k += 64) a = fmaf(r1s[k], LDR<T>::get(Wout, k), a);
        for (int off = 32; off; off >>= 1) a += __shfl_down(a, off, 64);
        if (tid == 0) {
            float res = a + LDR<T>::get(bout, 0);
            if (OUTF32) ((float*)out)[g] = res;
            else        ((bf16*)out)[g] = __float2bfloat16(res);
        }
    }
}

__global__ __launch_bounds__(256) void final_k(
    const int* flag, const float* gout,
    const void* Wr1, const void* br1, const void* Wout, const void* bout, void* out)
{
    __shared__ float r1s[HN];
    const int g = blockIdx.x, tid = threadIdx.x;
    if (*flag) final_impl<float, 1>(r1s, gout, Wr1, br1, Wout, bout, out, g, tid);
    else       final_impl<bf16,  0>(r1s, gout, Wr1, br1, Wout, bout, out, g, tid);
}

extern "C" void kernel_launch(void* const* d_in, const int* in_sizes, int n_in,
                              void* d_out, int out_size, void* d_ws, size_t ws_size,
                              hipStream_t stream)
{
    const void* nf      = d_in[0];
    const void* ef      = d_in[1];
    const int*  ei      = (const int*)d_in[2];
    const int*  bv      = (const int*)d_in[3];
    const void* W_in    = d_in[4];
    const void* b_in    = d_in[5];
    const void* W_edge  = d_in[6];
    const void* b_edge  = d_in[7];
    const void* W_tower = d_in[8];
    const void* W_mix   = d_in[9];
    const void* b_mix   = d_in[10];
    const void* Wz      = d_in[11];
    const void* Uz      = d_in[12];
    const void* bz      = d_in[13];
    const void* Wr      = d_in[14];
    const void* Ur      = d_in[15];
    const void* br      = d_in[16];
    const void* Wh      = d_in[17];
    const void* Uh      = d_in[18];
    const void* bh      = d_in[19];
    const void* W_score = d_in[20];
    const void* b_score = d_in[21];
    const void* W_feat  = d_in[22];
    const void* b_feat  = d_in[23];
    const void* W_r1    = d_in[24];
    const void* b_r1    = d_in[25];
    const void* W_out   = d_in[26];
    const void* b_out   = d_in[27];

    const int* src = ei;
    const int* dst = ei + EE;

    // ---- workspace layout (~115 MB) ----
    const size_t NH = (size_t)NN * HN;
    char* p = (char*)d_ws;
    auto take = [&](size_t bytes) { char* r = p; p += (bytes + 15) & ~(size_t)15; return r; };
    bf16*  h      = (bf16*)take(NH * 2);
    bf16*  aggb   = (bf16*)take(NH * 2);        // bf16 agg; feat reuses
    float* score  = (float*)take(NN * 4);
    float* ex     = (float*)take(NN * 4);
    unsigned* gmax_u = (unsigned*)take((GG + GG + GG * HN) * 4);
    float* gsum   = (float*)(gmax_u + GG);
    float* gout   = gsum + GG;
    short* WB     = (short*)take(WBSZ * 2);
    float* bpack  = (float*)take(3 * 208 * 4);
    short* WBmix  = (short*)take(7 * CTN * 512 * 2);
    float* bpmix  = (float*)take(208 * 4);
    short* WBfs   = (short*)take(7 * CTN * 512 * 2);
    float* bpfs   = (float*)take(208 * 4);
    short* WBin   = (short*)take(4 * CTN * 512 * 2);
    float* bpin   = (float*)take(208 * 4);
    float* Wef    = (float*)take(FE_ * HN * 4);
    float* bef    = (float*)take(HN * 4);
    short* WBedge = (short*)take(CTN * 512 * 2);
    float* bpedge = (float*)take(208 * 4);
    int*   cnt    = (int*)take(NN * 4);
    int*   off    = (int*)take((NN + 1) * 4);
    int*   cursor = (int*)take(NN * 4);
    int*   part   = (int*)take(512 * 4);
    int*   srcp   = (int*)take(EE * 4);
    int*   eidx   = (int*)take(EE * 4);
    bf16*  efp    = (bf16*)take((size_t)EE * FE_ * 2);
    int*   flag   = (int*)take(16);

    const dim3 blk(256);
    const int zsmall_n4 = (GG + GG + GG * HN) / 4;

    probe_k<<<dim3(1), blk, 0, stream>>>(nf, W_in, flag);

    pack_all_k<<<dim3((PA_TOT + 255) / 256), blk, 0, stream>>>(
        flag, Wz, Uz, bz, Wr, Ur, br, Wh, Uh, bh,
        W_tower, W_mix, b_mix, W_feat, b_feat, W_score, b_score,
        W_in, b_in, W_edge, b_edge,
        WB, bpack, WBmix, bpmix, WBfs, bpfs, WBin, bpin, Wef, bef,
        WBedge, bpedge);

    // CSR build + ef permute (once per launch)
    zero_k<<<dim3((NN / 4 + 255) / 256), blk, 0, stream>>>((float4*)cnt, NN / 4);
    hist_k<<<dim3(EE / 256), blk, 0, stream>>>(dst, cnt, EE);
    const int SB = (NN + 255) / 256;
    scan1_k<<<dim3(SB), blk, 0, stream>>>(cnt, off, part, NN);
    scan2_k<<<dim3(1), dim3(512), 0, stream>>>(part, SB);
    scan3_k<<<dim3(SB), blk, 0, stream>>>(part, off, cursor, NN, EE);
    fill_k<<<dim3(EE / 256), blk, 0, stream>>>(src, dst, cursor, srcp, eidx, EE);
    permute_k<<<dim3(EE / 256), blk, 0, stream>>>(flag, ef, eidx, efp, EE);

    // h = relu(nf @ W_in + b_in)
    gemmm_k<<<dim3(NN / 32), dim3(128), 0, stream>>>(
        flag, 2, nf, FN_, FN_, 4, WBin, bpin, 1, h, HN, (float*)nullptr, NN);

    for (int s = 0; s < STEPS_; s++) {
        msgw_k<<<dim3((NN + NPB - 1) / NPB), blk, 0, stream>>>(
            efp, srcp, off, h, WBedge, bpedge, aggb, NN);
        gru3_k<<<dim3((NN + MB3 - 1) / MB3), dim3(512), 0, stream>>>(
            aggb, h, WB, bpack, WBmix, bpmix, NN);
    }

    // readout: feat GEMM with fused score column
    zero_k<<<dim3((zsmall_n4 + 255) / 256), blk, 0, stream>>>((float4*)gmax_u, zsmall_n4);
    gemmm_k<<<dim3(NN / 32), dim3(128), 0, stream>>>(
        flag, 0, h, HN, HN, 7, WBfs, bpfs, 0, aggb, HN, score, NN);
    gmax_k<<<dim3((NN + 255) / 256), blk, 0, stream>>>(score, bv, gmax_u, NN);
    exsum_k<<<dim3((NN + 255) / 256), blk, 0, stream>>>(score, bv, gmax_u, ex, gsum, NN);
    scatter_k<<<dim3((NN + NRB - 1) / NRB), blk, 0, stream>>>(aggb, ex, gsum, bv, gout, NN);
    final_k<<<dim3(GG), blk, 0, stream>>>(flag, gout, W_r1, b_r1, W_out, b_out, d_out);
}